// Round 1
// baseline (1684.000 us; speedup 1.0000x reference)
//
#include <hip/hip_runtime.h>
#include <stdint.h>

typedef __attribute__((ext_vector_type(4))) int int32x4;

#define DEVI static __device__ __forceinline__

static constexpr int Bz = 16, Sz = 2048, Hz = 2048, Pz = 2048, NSTEP = 5;
static constexpr float QK_SCALE = 0.022097086912079608f; // 1/sqrt(2048)

// ---- byte extract (int8 -> float) ----
DEVI float xb0(int x){ return (float)(int8_t)(x); }
DEVI float xb1(int x){ return (float)(int8_t)(x>>8); }
DEVI float xb2(int x){ return (float)(int8_t)(x>>16); }
DEVI float xb3(int x){ return (float)(x>>24); }

DEVI float waveMax(float v){ for(int o=32;o;o>>=1) v=fmaxf(v,__shfl_down(v,o)); return v; }
DEVI float waveSum(float v){ for(int o=32;o;o>>=1) v+=__shfl_down(v,o); return v; }
DEVI double waveSumD(double v){ for(int o=32;o;o>>=1) v+=__shfl_down(v,o); return v; }
DEVI int waveSumI(int v){ for(int o=32;o;o>>=1) v+=__shfl_down(v,o); return v; }

// activation quant: round-half-even in double, clamp [-128,127]
DEVI int8_t qact(float v, double s){
  double q = rint((double)v*s);
  q = q>127.0 ? 127.0 : (q<-128.0 ? -128.0 : q);
  return (int8_t)(int)q;
}
// ternary weight quant: clip(round(w/g),-1,1) == (|w|>0.5g ? sign : 0) incl. half-even edge
DEVI int8_t tq(float v, double hg){
  double a = fabs((double)v);
  if (a > hg) return v > 0.f ? (int8_t)1 : (int8_t)-1;
  return (int8_t)0;
}

// ================= weight gamma: sum |w| in double =================
__global__ __launch_bounds__(256) void k_wabsum(const float* __restrict__ w, size_t n4,
                                                double* __restrict__ slot)
{
  size_t i0 = (size_t)blockIdx.x*256 + threadIdx.x;
  size_t stride = (size_t)gridDim.x*256;
  double s = 0.0;
  for (size_t i=i0;i<n4;i+=stride){
    float4 v = ((const float4*)w)[i];
    s += (double)fabsf(v.x) + (double)fabsf(v.y) + (double)fabsf(v.z) + (double)fabsf(v.w);
  }
  s = waveSumD(s);
  __shared__ double sd[4];
  int wave = threadIdx.x>>6, lane = threadIdx.x&63;
  if (lane==0) sd[wave]=s;
  __syncthreads();
  if (threadIdx.x==0) atomicAdd(slot, sd[0]+sd[1]+sd[2]+sd[3]);
}

// ================= weight quantize (normal [N][K] layout) =================
__global__ __launch_bounds__(256) void k_wquant4(const float* __restrict__ w, int8_t* __restrict__ q,
                                                 size_t n4, const double* __restrict__ slot,
                                                 double inv_count, float* __restrict__ gout, int gidx)
{
  double gamma = (*slot) * inv_count;
  if (gamma < 1e-5) gamma = 1e-5;
  double hg = 0.5*gamma;
  size_t i0 = (size_t)blockIdx.x*256 + threadIdx.x;
  size_t stride = (size_t)gridDim.x*256;
  for (size_t i=i0;i<n4;i+=stride){
    float4 v = ((const float4*)w)[i];
    char4 c;
    c.x = tq(v.x,hg); c.y = tq(v.y,hg); c.z = tq(v.z,hg); c.w = tq(v.w,hg);
    ((char4*)q)[i] = c;
  }
  if (i0==0) gout[gidx] = (float)gamma;
}

// ================= Wv quantize, transposed store: wqT[h][p] = tq(Wv[p][h]) =================
__global__ __launch_bounds__(256) void k_wquantT(const float* __restrict__ w, int8_t* __restrict__ wqT,
                                                 const double* __restrict__ slot, float* __restrict__ gout)
{
  double gamma = (*slot) * (1.0/((double)Pz*(double)Hz));
  if (gamma < 1e-5) gamma = 1e-5;
  double hg = 0.5*gamma;
  size_t n4 = (size_t)Pz*Hz/4;
  size_t i0 = (size_t)blockIdx.x*256 + threadIdx.x;
  size_t stride = (size_t)gridDim.x*256;
  for (size_t i=i0;i<n4;i+=stride){
    float4 v = ((const float4*)w)[i];
    size_t idx = i*4;
    int p = (int)(idx / Hz);
    int h = (int)(idx % Hz);
    wqT[(size_t)(h+0)*Pz + p] = tq(v.x,hg);
    wqT[(size_t)(h+1)*Pz + p] = tq(v.y,hg);
    wqT[(size_t)(h+2)*Pz + p] = tq(v.z,hg);
    wqT[(size_t)(h+3)*Pz + p] = tq(v.w,hg);
  }
  if (i0==0) gout[5] = (float)gamma;
}

// ================= Wg (5 tiny rows): per-row gamma + quantize =================
__global__ __launch_bounds__(256) void k_wgquant(const float* __restrict__ wg, int8_t* __restrict__ wgq,
                                                 float* __restrict__ gout)
{
  int i = blockIdx.x, tid = threadIdx.x;
  int wave = tid>>6, lane = tid&63;
  const float* wr = wg + (size_t)i*Pz;
  float vals[8]; double s = 0.0;
  #pragma unroll
  for (int j=0;j<8;++j){ vals[j] = wr[tid + j*256]; s += (double)fabsf(vals[j]); }
  s = waveSumD(s);
  __shared__ double sd[4];
  if (lane==0) sd[wave]=s;
  __syncthreads();
  double gamma = (sd[0]+sd[1]+sd[2]+sd[3]) * (1.0/(double)Pz);
  if (gamma < 1e-5) gamma = 1e-5;
  double hg = 0.5*gamma;
  #pragma unroll
  for (int j=0;j<8;++j) wgq[(size_t)i*Pz + tid + j*256] = tq(vals[j],hg);
  if (tid==0) gout[9+i] = (float)gamma;
}

// ================= per-row activation quantize (cols = NV*1024) =================
template<int NV>
__global__ __launch_bounds__(256) void k_quant_rows(const float* __restrict__ x, int8_t* __restrict__ xq,
                                                    float* __restrict__ rs)
{
  int row = blockIdx.x, tid = threadIdx.x;
  int wave = tid>>6, lane = tid&63;
  const float4* xr = (const float4*)(x + (size_t)row*(NV*1024));
  float4 v[NV];
  float amax = 0.f;
  #pragma unroll
  for (int i=0;i<NV;++i){
    v[i] = xr[tid + i*256];
    amax = fmaxf(amax, fmaxf(fmaxf(fabsf(v[i].x),fabsf(v[i].y)),fmaxf(fabsf(v[i].z),fabsf(v[i].w))));
  }
  amax = waveMax(amax);
  __shared__ float sm[4];
  if (lane==0) sm[wave]=amax;
  __syncthreads();
  float M = fmaxf(fmaxf(sm[0],sm[1]),fmaxf(sm[2],sm[3]));
  double Md = (double)M; if (Md < 1e-5) Md = 1e-5;
  double s = 127.0/Md;
  char4* o4 = (char4*)(xq + (size_t)row*(NV*1024));
  #pragma unroll
  for (int i=0;i<NV;++i){
    char4 c;
    c.x = qact(v[i].x,s); c.y = qact(v[i].y,s); c.z = qact(v[i].z,s); c.w = qact(v[i].w,s);
    o4[tid + i*256] = c;
  }
  if (tid==0) rs[row] = (float)(Md/127.0);
}

// ================= 16-row int8 GEMM via MFMA: out[m,n] = acc*rs[m]*gamma (+bias)(epilogue) ==
// A: [16][K] int8 row-major; Bq: [N][K] int8 row-major. EPI: 0 plain, 1 tanh, 2 add plan.
template<int K, int EPI>
__global__ __launch_bounds__(256) void k_gemm16(const int8_t* __restrict__ aq, const float* __restrict__ ars,
                                                const int8_t* __restrict__ bq, const float* __restrict__ gslot,
                                                const float* __restrict__ bias, const float* __restrict__ addsrc,
                                                float* __restrict__ out, int N)
{
  int wave = threadIdx.x>>6, lane = threadIdx.x&63;
  int n0 = blockIdx.x*64 + wave*16;
  int ra = lane&15, kg = lane>>4;
  const int8_t* ap = aq + (size_t)ra*K + kg*16;
  const int8_t* bp = bq + (size_t)(n0+ra)*K + kg*16;
  int32x4 acc = {0,0,0,0};
#pragma unroll 8
  for (int k=0;k<K;k+=64){
    int32x4 a = *(const int32x4*)(ap + k);
    int32x4 b = *(const int32x4*)(bp + k);
    acc = __builtin_amdgcn_mfma_i32_16x16x64_i8(a, b, acc, 0, 0, 0);
  }
  float g = *gslot;
  int col = n0 + (lane&15);
  int mbase = (lane>>4)*4;
#pragma unroll
  for (int r=0;r<4;++r){
    int m = mbase + r;
    float y = (float)acc[r] * ars[m] * g;
    if (bias) y += bias[col];
    if (EPI==1) y = tanhf(y);
    if (EPI==2) y += addsrc[(size_t)m*Pz + col];
    out[(size_t)m*N + col] = y;
  }
}

// ================= t_partial: tpart[pc][b][h] = sum_{p in chunk} q[b][p]*wqk[p][h] ==========
__global__ __launch_bounds__(256) void k_tpart(const float* __restrict__ q, const int8_t* __restrict__ wqk,
                                               float* __restrict__ tpart)
{
  int b = blockIdx.y, pc = blockIdx.x, tid = threadIdx.x;
  __shared__ float qs[256];
  qs[tid] = q[(size_t)b*Pz + pc*256 + tid];
  __syncthreads();
  float acc[8] = {0,0,0,0,0,0,0,0};
  const int8_t* wb = wqk + (size_t)pc*256*Hz;
  for (int p=0;p<256;++p){
    float qv = qs[p];
    const int* wr = (const int*)(wb + (size_t)p*Hz);
    int w0 = wr[tid], w1 = wr[256+tid];
    acc[0] += qv*xb0(w0); acc[1] += qv*xb1(w0); acc[2] += qv*xb2(w0); acc[3] += qv*xb3(w0);
    acc[4] += qv*xb0(w1); acc[5] += qv*xb1(w1); acc[6] += qv*xb2(w1); acc[7] += qv*xb3(w1);
  }
  float* tp = tpart + ((size_t)pc*Bz + b)*Hz;
  #pragma unroll
  for (int j=0;j<4;++j){ tp[tid*4+j] = acc[j]; tp[1024 + tid*4 + j] = acc[4+j]; }
}

__global__ __launch_bounds__(256) void k_treduce(const float* __restrict__ tpart, float* __restrict__ t)
{
  int idx = blockIdx.x*256 + threadIdx.x;
  float s = 0.f;
  #pragma unroll
  for (int pc=0;pc<8;++pc) s += tpart[(size_t)pc*Bz*Hz + idx];
  t[idx] = s;
}

// ================= scores[b,s] = (sum_h xq_mem[b,s,h]*t[b,h]) * rs_mem[b,s] * gk * SCALE ====
__global__ __launch_bounds__(256) void k_scores(const int8_t* __restrict__ xq_mem, const float* __restrict__ t,
                                                const float* __restrict__ rs_mem, const float* __restrict__ gk,
                                                float* __restrict__ scores)
{
  int b = blockIdx.y; int s0 = blockIdx.x*64;
  int wave = threadIdx.x>>6, lane = threadIdx.x&63;
  const float4* t4 = (const float4*)(t + (size_t)b*Hz);
  float gs = (*gk) * QK_SCALE;
  for (int s = s0 + wave; s < s0 + 64; s += 4){
    const int8_t* xr = xq_mem + ((size_t)b*Sz + s)*Hz;
    float acc = 0.f;
    #pragma unroll
    for (int i=0;i<4;++i){
      int h = i*512 + lane*8;
      int2 xw = *(const int2*)(xr + h);
      float4 ta = t4[h/4], tb = t4[h/4 + 1];
      acc += ta.x*xb0(xw.x) + ta.y*xb1(xw.x) + ta.z*xb2(xw.x) + ta.w*xb3(xw.x)
           + tb.x*xb0(xw.y) + tb.y*xb1(xw.y) + tb.z*xb2(xw.y) + tb.w*xb3(xw.y);
    }
    acc = waveSum(acc);
    if (lane==0) scores[(size_t)b*Sz + s] = acc * rs_mem[(size_t)b*Sz + s] * gs;
  }
}

// ================= row softmax over S=2048 =================
__global__ __launch_bounds__(256) void k_softmax(const float* __restrict__ x, float* __restrict__ y)
{
  int b = blockIdx.x, tid = threadIdx.x;
  int wave = tid>>6, lane = tid&63;
  float v[8]; float m = -3.4e38f;
  #pragma unroll
  for (int j=0;j<8;++j){ v[j] = x[(size_t)b*Sz + tid + j*256]; m = fmaxf(m, v[j]); }
  m = waveMax(m);
  __shared__ float sm[4]; __shared__ float ss[4];
  if (lane==0) sm[wave]=m;
  __syncthreads();
  float M = fmaxf(fmaxf(sm[0],sm[1]),fmaxf(sm[2],sm[3]));
  float e[8]; float s = 0.f;
  #pragma unroll
  for (int j=0;j<8;++j){ e[j] = expf(v[j]-M); s += e[j]; }
  s = waveSum(s);
  if (lane==0) ss[wave]=s;
  __syncthreads();
  float Z = ss[0]+ss[1]+ss[2]+ss[3];
  #pragma unroll
  for (int j=0;j<8;++j) y[(size_t)b*Sz + tid + j*256] = e[j]/Z;
}

// ================= u_partial: upart[sc][b][h] = sum_{s in chunk} aw*rs*xq_mem[b,s,h] =========
__global__ __launch_bounds__(256) void k_upart(const int8_t* __restrict__ xq_mem, const float* __restrict__ aw,
                                               const float* __restrict__ rs_mem, float* __restrict__ upart)
{
  int b = blockIdx.y, sc = blockIdx.x, tid = threadIdx.x;
  __shared__ float wl[256];
  int sbase = sc*256;
  wl[tid] = aw[(size_t)b*Sz + sbase + tid] * rs_mem[(size_t)b*Sz + sbase + tid];
  __syncthreads();
  float acc[8] = {0,0,0,0,0,0,0,0};
  const int8_t* xbp = xq_mem + ((size_t)b*Sz + sbase)*Hz;
  for (int s=0;s<256;++s){
    float w = wl[s];
    const int* xr = (const int*)(xbp + (size_t)s*Hz);
    int x0 = xr[tid], x1 = xr[256+tid];
    acc[0] += w*xb0(x0); acc[1] += w*xb1(x0); acc[2] += w*xb2(x0); acc[3] += w*xb3(x0);
    acc[4] += w*xb0(x1); acc[5] += w*xb1(x1); acc[6] += w*xb2(x1); acc[7] += w*xb3(x1);
  }
  float* up = upart + ((size_t)sc*Bz + b)*Hz;
  #pragma unroll
  for (int j=0;j<4;++j){ up[tid*4+j] = acc[j]; up[1024 + tid*4 + j] = acc[4+j]; }
}

// ================= ctx_partial: ctxpart[hc][b][p] = gv * sum_{h in chunk} u[b,h]*wqvT[h][p] ==
__global__ __launch_bounds__(256) void k_ctxpart(const float* __restrict__ upart, const int8_t* __restrict__ wqvT,
                                                 const float* __restrict__ gv, float* __restrict__ ctxpart)
{
  int b = blockIdx.y, hc = blockIdx.x, tid = threadIdx.x;
  __shared__ float ul[256];
  float us = 0.f;
  #pragma unroll
  for (int sc=0;sc<8;++sc) us += upart[((size_t)sc*Bz + b)*Hz + hc*256 + tid];
  ul[tid] = us;
  __syncthreads();
  float acc[8] = {0,0,0,0,0,0,0,0};
  const int8_t* wb = wqvT + (size_t)hc*256*Pz;
  for (int h=0;h<256;++h){
    float uv = ul[h];
    const int* wr = (const int*)(wb + (size_t)h*Pz);
    int w0 = wr[tid], w1 = wr[256+tid];
    acc[0] += uv*xb0(w0); acc[1] += uv*xb1(w0); acc[2] += uv*xb2(w0); acc[3] += uv*xb3(w0);
    acc[4] += uv*xb0(w1); acc[5] += uv*xb1(w1); acc[6] += uv*xb2(w1); acc[7] += uv*xb3(w1);
  }
  float g = *gv;
  float* cp = ctxpart + ((size_t)hc*Bz + b)*Pz;
  #pragma unroll
  for (int j=0;j<4;++j){ cp[tid*4+j] = acc[j]*g; cp[1024 + tid*4 + j] = acc[4+j]*g; }
}

// ================= concat [plan | ctx] + row-quantize over 4096 =================
__global__ __launch_bounds__(256) void k_catquant(const float* __restrict__ plan, const float* __restrict__ ctxpart,
                                                  int8_t* __restrict__ xq, float* __restrict__ rs)
{
  int b = blockIdx.x, tid = threadIdx.x;
  int wave = tid>>6, lane = tid&63;
  float pv[8], cv[8];
  float amax = 0.f;
  #pragma unroll
  for (int j=0;j<8;++j){
    int p = tid + j*256;
    pv[j] = plan[(size_t)b*Pz + p];
    float c = 0.f;
    #pragma unroll
    for (int hc=0;hc<8;++hc) c += ctxpart[((size_t)hc*Bz + b)*Pz + p];
    cv[j] = c;
    amax = fmaxf(amax, fmaxf(fabsf(pv[j]), fabsf(cv[j])));
  }
  amax = waveMax(amax);
  __shared__ float sm[4];
  if (lane==0) sm[wave]=amax;
  __syncthreads();
  float M = fmaxf(fmaxf(sm[0],sm[1]),fmaxf(sm[2],sm[3]));
  double Md = (double)M; if (Md < 1e-5) Md = 1e-5;
  double s = 127.0/Md;
  #pragma unroll
  for (int j=0;j<8;++j){
    int p = tid + j*256;
    xq[(size_t)b*2*Pz + p]      = qact(pv[j], s);
    xq[(size_t)b*2*Pz + Pz + p] = qact(cv[j], s);
  }
  if (tid==0) rs[b] = (float)(Md/127.0);
}

// ================= fused GRU cell + state quantize + gate logit =================
__global__ __launch_bounds__(256) void k_gru(const float* __restrict__ gi, const float* __restrict__ gh,
                                             const float* __restrict__ b_ih, const float* __restrict__ b_hh,
                                             float* __restrict__ plan, int8_t* __restrict__ xq_plan,
                                             float* __restrict__ rs_plan, const int8_t* __restrict__ wgq,
                                             const float* __restrict__ gammas, const float* __restrict__ bg,
                                             float* __restrict__ logits, float* __restrict__ d_states,
                                             float* __restrict__ flatbuf, int step)
{
  int b = blockIdx.x, tid = threadIdx.x;
  int wave = tid>>6, lane = tid&63;
  float hn[8];
  float amax = 0.f;
  #pragma unroll
  for (int j=0;j<8;++j){
    int p = tid + j*256;
    float ir = gi[(size_t)b*3*Pz + p]        + b_ih[p];
    float iz = gi[(size_t)b*3*Pz + Pz + p]   + b_ih[Pz+p];
    float in_= gi[(size_t)b*3*Pz + 2*Pz + p] + b_ih[2*Pz+p];
    float hr = gh[(size_t)b*3*Pz + p]        + b_hh[p];
    float hz = gh[(size_t)b*3*Pz + Pz + p]   + b_hh[Pz+p];
    float hv = gh[(size_t)b*3*Pz + 2*Pz + p] + b_hh[2*Pz+p];
    float r = 1.f/(1.f + expf(-(ir+hr)));
    float z = 1.f/(1.f + expf(-(iz+hz)));
    float n = tanhf(in_ + r*hv);
    float hp = plan[(size_t)b*Pz + p];
    hn[j] = (1.f - z)*n + z*hp;
    amax = fmaxf(amax, fabsf(hn[j]));
  }
  amax = waveMax(amax);
  __shared__ float sm[4];
  if (lane==0) sm[wave]=amax;
  __syncthreads();
  float M = fmaxf(fmaxf(sm[0],sm[1]),fmaxf(sm[2],sm[3]));
  double Md = (double)M; if (Md < 1e-5) Md = 1e-5;
  double s = 127.0/Md;
  int lsum = 0;
  #pragma unroll
  for (int j=0;j<8;++j){
    int p = tid + j*256;
    float h = hn[j];
    plan[(size_t)b*Pz + p] = h;
    d_states[(size_t)b*Pz + p] = h;
    flatbuf[(size_t)b*NSTEP*Pz + (size_t)step*Pz + p] = h;
    double qd = rint((double)h*s);
    qd = qd>127.0 ? 127.0 : (qd<-128.0 ? -128.0 : qd);
    int qv = (int)qd;
    xq_plan[(size_t)b*Pz + p] = (int8_t)qv;
    lsum += qv * (int)wgq[(size_t)step*Pz + p];
  }
  lsum = waveSumI(lsum);
  __shared__ int si[4];
  if (lane==0) si[wave]=lsum;
  __syncthreads();
  if (tid==0){
    int L = si[0]+si[1]+si[2]+si[3];
    logits[b*NSTEP + step] = (float)((double)L * (Md/127.0) * (double)gammas[9+step]) + bg[step];
    rs_plan[b] = (float)(Md/127.0);
  }
}

// ================= importance softmax over 5 steps =================
__global__ void k_imp(const float* __restrict__ logits, float* __restrict__ out)
{
  int tid = threadIdx.x;
  if (tid < Bz){
    float v[NSTEP]; float m = -3.4e38f;
    for (int i=0;i<NSTEP;++i){ v[i] = logits[tid*NSTEP+i]; m = fmaxf(m, v[i]); }
    float e[NSTEP]; float s = 0.f;
    for (int i=0;i<NSTEP;++i){ e[i] = expf(v[i]-m); s += e[i]; }
    for (int i=0;i<NSTEP;++i) out[tid*NSTEP+i] = e[i]/s;
  }
}

// ======================================================================
extern "C" void kernel_launch(void* const* d_in, const int* in_sizes, int n_in,
                              void* d_out, int out_size, void* d_ws, size_t ws_size,
                              hipStream_t stream)
{
  (void)in_sizes; (void)n_in; (void)out_size; (void)ws_size;
  const float* context_state  = (const float*)d_in[0];
  const float* context_memory = (const float*)d_in[1];
  const float* W_enc = (const float*)d_in[2];
  const float* b_enc = (const float*)d_in[3];
  const float* W_ih  = (const float*)d_in[4];
  const float* W_hh  = (const float*)d_in[5];
  const float* b_ih  = (const float*)d_in[6];
  const float* b_hh  = (const float*)d_in[7];
  const float* Wq    = (const float*)d_in[8];
  const float* Wk    = (const float*)d_in[9];
  const float* Wv    = (const float*)d_in[10];
  const float* Wc    = (const float*)d_in[11];
  const float* bc    = (const float*)d_in[12];
  const float* W_agg = (const float*)d_in[13];
  const float* b_agg = (const float*)d_in[14];
  const float* W_out = (const float*)d_in[15];
  const float* b_out = (const float*)d_in[16];
  const float* Wg    = (const float*)d_in[17];
  const float* bg    = (const float*)d_in[18];
  float* out = (float*)d_out;

  uint8_t* base = (uint8_t*)d_ws;
  size_t cur = 0;
  auto take = [&](size_t bytes)->uint8_t*{
    uint8_t* p = base + cur;
    cur += (bytes + 255) & ~(size_t)255;
    return p;
  };
  double* absum   = (double*)take(9*sizeof(double));
  float*  gammas  = (float*)take(16*sizeof(float));   // 0..8 big mats, 9..13 Wg steps
  int8_t* wq_enc  = (int8_t*)take((size_t)Pz*Hz);
  int8_t* wq_ih   = (int8_t*)take((size_t)3*Pz*Pz);
  int8_t* wq_hh   = (int8_t*)take((size_t)3*Pz*Pz);
  int8_t* wq_q    = (int8_t*)take((size_t)Pz*Pz);
  int8_t* wq_k    = (int8_t*)take((size_t)Pz*Hz);
  int8_t* wq_vT   = (int8_t*)take((size_t)Hz*Pz);
  int8_t* wq_c    = (int8_t*)take((size_t)Pz*2*Pz);
  int8_t* wq_agg  = (int8_t*)take((size_t)Pz*NSTEP*Pz);
  int8_t* wq_out  = (int8_t*)take((size_t)Hz*Pz);
  int8_t* wq_g    = (int8_t*)take((size_t)NSTEP*Pz);
  int8_t* xq_mem  = (int8_t*)take((size_t)Bz*Sz*Hz);
  float*  rs_mem  = (float*)take((size_t)Bz*Sz*4);
  int8_t* xq_cs   = (int8_t*)take((size_t)Bz*Hz);
  float*  rs_cs   = (float*)take(Bz*4);
  float*  plan    = (float*)take((size_t)Bz*Pz*4);
  int8_t* xq_plan = (int8_t*)take((size_t)Bz*Pz);
  float*  rs_plan = (float*)take(Bz*4);
  float*  qbuf    = (float*)take((size_t)Bz*Pz*4);
  float*  tpart   = (float*)take((size_t)8*Bz*Hz*4);
  float*  tbuf    = (float*)take((size_t)Bz*Hz*4);
  float*  scores  = (float*)take((size_t)Bz*Sz*4);
  float*  aw      = (float*)take((size_t)Bz*Sz*4);
  float*  upart   = (float*)take((size_t)8*Bz*Hz*4);
  float*  ctxpart = (float*)take((size_t)8*Bz*Pz*4);
  int8_t* xq_cat  = (int8_t*)take((size_t)Bz*2*Pz);
  float*  rs_cat  = (float*)take(Bz*4);
  float*  xbuf    = (float*)take((size_t)Bz*Pz*4);
  int8_t* xq_x    = (int8_t*)take((size_t)Bz*Pz);
  float*  rs_x    = (float*)take(Bz*4);
  float*  gi      = (float*)take((size_t)Bz*3*Pz*4);
  float*  gh      = (float*)take((size_t)Bz*3*Pz*4);
  float*  flatbuf = (float*)take((size_t)Bz*NSTEP*Pz*4);
  int8_t* xq_flat = (int8_t*)take((size_t)Bz*NSTEP*Pz);
  float*  rs_flat = (float*)take(Bz*4);
  float*  aggbuf  = (float*)take((size_t)Bz*Pz*4);
  int8_t* xq_agg  = (int8_t*)take((size_t)Bz*Pz);
  float*  rs_agg  = (float*)take(Bz*4);
  float*  logits  = (float*)take((size_t)Bz*NSTEP*4);

  // ---- weight gammas + ternary quantize ----
  hipMemsetAsync(absum, 0, 9*sizeof(double), stream);
  const float* wsrc[9] = {W_enc, W_ih, W_hh, Wq, Wk, Wv, Wc, W_agg, W_out};
  size_t wn[9] = {(size_t)Pz*Hz, (size_t)3*Pz*Pz, (size_t)3*Pz*Pz, (size_t)Pz*Pz,
                  (size_t)Pz*Hz, (size_t)Pz*Hz, (size_t)Pz*2*Pz, (size_t)Pz*NSTEP*Pz, (size_t)Hz*Pz};
  for (int i=0;i<9;++i)
    k_wabsum<<<512,256,0,stream>>>(wsrc[i], wn[i]/4, absum+i);
  int8_t* wqdst[9] = {wq_enc, wq_ih, wq_hh, wq_q, wq_k, nullptr, wq_c, wq_agg, wq_out};
  for (int i=0;i<9;++i){
    if (i==5) continue;
    k_wquant4<<<512,256,0,stream>>>(wsrc[i], wqdst[i], wn[i]/4, absum+i, 1.0/(double)wn[i], gammas, i);
  }
  k_wquantT<<<512,256,0,stream>>>(Wv, wq_vT, absum+5, gammas);
  k_wgquant<<<NSTEP,256,0,stream>>>(Wg, wq_g, gammas);

  // ---- activation quantize: context_state, context_memory ----
  k_quant_rows<2><<<Bz,256,0,stream>>>(context_state, xq_cs, rs_cs);
  k_quant_rows<2><<<Bz*Sz,256,0,stream>>>(context_memory, xq_mem, rs_mem);

  // ---- plan_state = tanh(bit_linear(context_state, W_enc, b_enc)) ----
  k_gemm16<2048,1><<<32,256,0,stream>>>(xq_cs, rs_cs, wq_enc, gammas+0, b_enc, nullptr, plan, Pz);
  k_quant_rows<2><<<Bz,256,0,stream>>>(plan, xq_plan, rs_plan);

  // ---- 5 planning steps ----
  for (int step=0; step<NSTEP; ++step){
    // q = bit_linear(plan, Wq)
    k_gemm16<2048,0><<<32,256,0,stream>>>(xq_plan, rs_plan, wq_q, gammas+3, nullptr, nullptr, qbuf, Pz);
    // t = q @ ternary(Wk)  (k folded algebraically)
    k_tpart<<<dim3(8,Bz),256,0,stream>>>(qbuf, wq_k, tpart);
    k_treduce<<<(Bz*Hz)/256,256,0,stream>>>(tpart, tbuf);
    // scores + softmax
    k_scores<<<dim3(Sz/64,Bz),256,0,stream>>>(xq_mem, tbuf, rs_mem, gammas+4, scores);
    k_softmax<<<Bz,256,0,stream>>>(scores, aw);
    // u = sum_s aw*rs*xq_mem ; ctx = gv * u @ ternary(Wv)^T (v folded algebraically)
    k_upart<<<dim3(8,Bz),256,0,stream>>>(xq_mem, aw, rs_mem, upart);
    k_ctxpart<<<dim3(8,Bz),256,0,stream>>>(upart, wq_vT, gammas+5, ctxpart);
    // concat + quantize, comb = bit_linear(cat, Wc, bc); x = plan + comb
    k_catquant<<<Bz,256,0,stream>>>(plan, ctxpart, xq_cat, rs_cat);
    k_gemm16<4096,2><<<32,256,0,stream>>>(xq_cat, rs_cat, wq_c, gammas+6, bc, plan, xbuf, Pz);
    k_quant_rows<2><<<Bz,256,0,stream>>>(xbuf, xq_x, rs_x);
    // GRU gates (biases folded into k_gru)
    k_gemm16<2048,0><<<96,256,0,stream>>>(xq_x, rs_x, wq_ih, gammas+1, nullptr, nullptr, gi, 3*Pz);
    k_gemm16<2048,0><<<96,256,0,stream>>>(xq_plan, rs_plan, wq_hh, gammas+2, nullptr, nullptr, gh, 3*Pz);
    k_gru<<<Bz,256,0,stream>>>(gi, gh, b_ih, b_hh, plan, xq_plan, rs_plan, wq_g, gammas, bg,
                               logits, out + 32768 + (size_t)step*Bz*Pz, flatbuf, step);
  }

  // ---- aggregate + output projection + importance softmax ----
  k_quant_rows<10><<<Bz,256,0,stream>>>(flatbuf, xq_flat, rs_flat);
  k_gemm16<10240,1><<<32,256,0,stream>>>(xq_flat, rs_flat, wq_agg, gammas+7, b_agg, nullptr, aggbuf, Pz);
  k_quant_rows<2><<<Bz,256,0,stream>>>(aggbuf, xq_agg, rs_agg);
  k_gemm16<2048,0><<<32,256,0,stream>>>(xq_agg, rs_agg, wq_out, gammas+8, b_out, nullptr, out, Hz);
  k_imp<<<1,64,0,stream>>>(logits, out + 32768 + (size_t)NSTEP*Bz*Pz);
}